// Round 2
// baseline (1563.095 us; speedup 1.0000x reference)
//
#include <hip/hip_runtime.h>
#include <stdint.h>

#define TTOK 16384
#define NDIM 1024
#define NHID 2048
#define NEXP 8
#define TM 128
#define BKK 64
#define MAXTILES 264
#define SLOTCAP (2 * TTOK + NEXP * TM) /* 33792 */

typedef __attribute__((ext_vector_type(8))) short short8;
typedef __attribute__((ext_vector_type(4))) float f32x4;

__device__ __forceinline__ unsigned short f2bf(float f) {
  unsigned int u = __float_as_uint(f);
  u += 0x7FFFu + ((u >> 16) & 1u);
  return (unsigned short)(u >> 16);
}

__device__ __forceinline__ void gload16(const void* g, void* l) {
  __builtin_amdgcn_global_load_lds(
      (const __attribute__((address_space(1))) unsigned int*)g,
      (__attribute__((address_space(3))) unsigned int*)l, 16, 0, 0);
}

__device__ __forceinline__ float silu(float z) {
  return z / (1.0f + __expf(-z));
}

// ---------------------------------------------------------------------------
// Router: one wave per token. f32 logits, softmax, top-2, renorm gates.
// Also converts the x row to bf16 into ws.
// ---------------------------------------------------------------------------
__global__ void k_router(const float* __restrict__ x, const float* __restrict__ rw,
                         unsigned short* __restrict__ xbf, int* __restrict__ tok_e,
                         float* __restrict__ tok_gw, unsigned int* __restrict__ counts) {
  int t = (blockIdx.x << 2) + (threadIdx.x >> 6);
  int lane = threadIdx.x & 63;
  const float4* xr = (const float4*)(x + (size_t)t * NDIM);

  float4 v[4];
  float d[NEXP];
#pragma unroll
  for (int e = 0; e < NEXP; ++e) d[e] = 0.f;

#pragma unroll
  for (int i = 0; i < 4; ++i) {
    int c = i * 64 + lane;
    v[i] = xr[c];
#pragma unroll
    for (int e = 0; e < NEXP; ++e) {
      float4 w = ((const float4*)(rw + e * NDIM))[c];
      d[e] += v[i].x * w.x + v[i].y * w.y + v[i].z * w.z + v[i].w * w.w;
    }
  }
#pragma unroll
  for (int e = 0; e < NEXP; ++e)
    for (int s = 32; s; s >>= 1) d[e] += __shfl_xor(d[e], s, 64);

  // bf16 row out
  unsigned short* xo = xbf + (size_t)t * NDIM;
#pragma unroll
  for (int i = 0; i < 4; ++i) {
    int c = i * 64 + lane;
    ushort4 u;
    u.x = f2bf(v[i].x); u.y = f2bf(v[i].y); u.z = f2bf(v[i].z); u.w = f2bf(v[i].w);
    ((ushort4*)xo)[c] = u;
  }

  if (lane == 0) {
    float m = d[0];
#pragma unroll
    for (int e = 1; e < NEXP; ++e) m = fmaxf(m, d[e]);
    float ex[NEXP];
#pragma unroll
    for (int e = 0; e < NEXP; ++e) ex[e] = __expf(d[e] - m);
    int e0 = 0;
#pragma unroll
    for (int e = 1; e < NEXP; ++e) if (ex[e] > ex[e0]) e0 = e;
    int e1 = (e0 == 0) ? 1 : 0;
#pragma unroll
    for (int e = 0; e < NEXP; ++e) if (e != e0 && ex[e] > ex[e1]) e1 = e;
    float p0 = ex[e0], p1 = ex[e1];
    float inv = 1.f / (p0 + p1);
    tok_e[2 * t] = e0; tok_e[2 * t + 1] = e1;
    tok_gw[2 * t] = p0 * inv; tok_gw[2 * t + 1] = p1 * inv;
    atomicAdd(&counts[e0], 1u);
    atomicAdd(&counts[e1], 1u);
  }
}

// ---------------------------------------------------------------------------
// Offsets + tile table (single thread; <300 iterations)
// ---------------------------------------------------------------------------
__global__ void k_offsets(const unsigned int* __restrict__ counts,
                          unsigned int* __restrict__ slotbase,
                          unsigned int* __restrict__ tile_e, unsigned int* __restrict__ tile_m0,
                          unsigned int* __restrict__ n_tiles) {
  if (threadIdx.x == 0 && blockIdx.x == 0) {
    unsigned int base = 0, nt = 0;
    for (int e = 0; e < NEXP; ++e) {
      slotbase[e] = base;
      unsigned int tiles = (counts[e] + TM - 1) / TM;
      for (unsigned int i = 0; i < tiles && nt < MAXTILES; ++i) {
        tile_e[nt] = (unsigned)e;
        tile_m0[nt] = base + i * TM;
        ++nt;
      }
      base += tiles * TM;
    }
    *n_tiles = nt;
  }
}

// ---------------------------------------------------------------------------
// Stable (token-order) compaction into per-expert slot lists + padding.
// One block per expert; ballot-scan.
// ---------------------------------------------------------------------------
__global__ void k_fill(const int* __restrict__ tok_e, const float* __restrict__ tok_gw,
                       const unsigned int* __restrict__ counts,
                       const unsigned int* __restrict__ slotbase,
                       unsigned int* __restrict__ tok_list, float* __restrict__ gate_list) {
  int e = blockIdx.x;
  int tid = threadIdx.x, w = tid >> 6, lane = tid & 63;
  __shared__ unsigned int s_wt[4];
  __shared__ unsigned int s_run;
  if (tid == 0) s_run = 0;
  __syncthreads();
  unsigned int base = slotbase[e];
  for (int c0 = 0; c0 < TTOK; c0 += 256) {
    int t = c0 + tid;
    int f0 = (tok_e[2 * t] == e);
    int f1 = (tok_e[2 * t + 1] == e);
    int f = f0 | f1;
    float g = f0 ? tok_gw[2 * t] : tok_gw[2 * t + 1];
    unsigned long long m = __ballot(f);
    unsigned int excl =
        (unsigned int)__popcll(m & (((unsigned long long)2 << lane) - 1)) - (unsigned)f;
    if (lane == 63) s_wt[w] = (unsigned int)__popcll(m);
    __syncthreads();
    unsigned int wbase = 0;
    for (int i = 0; i < 4; ++i) if (i < w) wbase += s_wt[i];
    unsigned int tot = s_wt[0] + s_wt[1] + s_wt[2] + s_wt[3];
    unsigned int pos = s_run + wbase + excl;
    if (f) { tok_list[base + pos] = (unsigned)t; gate_list[base + pos] = g; }
    __syncthreads();
    if (tid == 0) s_run += tot;
    __syncthreads();
  }
  unsigned int cnt = counts[e];
  unsigned int cap = ((cnt + TM - 1) / TM) * TM;
  for (unsigned int i = cnt + tid; i < cap; i += 256) {
    tok_list[base + i] = 0u;
    gate_list[base + i] = 0.f;
  }
}

// ---------------------------------------------------------------------------
// Transpose + f32->bf16 convert: src [b][R][C] f32 -> dst [b][C][R] bf16
// ---------------------------------------------------------------------------
__global__ void k_tconv(const float* __restrict__ src, unsigned short* __restrict__ dst,
                        int R, int C) {
  int b = blockIdx.z;
  src += (size_t)b * R * C;
  dst += (size_t)b * R * C;
  __shared__ unsigned short tile[64][65];
  int bx = blockIdx.x * 64, by = blockIdx.y * 64;
  int tx = threadIdx.x & 15, ty = threadIdx.x >> 4;
#pragma unroll
  for (int rr = 0; rr < 4; ++rr) {
    int rl = rr * 16 + ty;
    float4 v = *(const float4*)(src + (size_t)(by + rl) * C + bx + tx * 4);
    tile[rl][tx * 4 + 0] = f2bf(v.x);
    tile[rl][tx * 4 + 1] = f2bf(v.y);
    tile[rl][tx * 4 + 2] = f2bf(v.z);
    tile[rl][tx * 4 + 3] = f2bf(v.w);
  }
  __syncthreads();
#pragma unroll
  for (int rr = 0; rr < 4; ++rr) {
    int cl = rr * 16 + ty;  // local out-row (= src col)
    ushort4 u;
    u.x = tile[tx * 4 + 0][cl];
    u.y = tile[tx * 4 + 1][cl];
    u.z = tile[tx * 4 + 2][cl];
    u.w = tile[tx * 4 + 3][cl];
    *(ushort4*)(dst + (size_t)(bx + cl) * R + by + tx * 4) = u;
  }
}

// ---------------------------------------------------------------------------
// Sentinel: reveals ws_size (in MB) through absmax if ws is too small.
// ---------------------------------------------------------------------------
__global__ void k_sentinel(float* __restrict__ out, float v) {
  if (threadIdx.x == 0 && blockIdx.x == 0) out[0] = v;
}

// ---------------------------------------------------------------------------
// GEMM12: H[slot][hid] = silu(Xg @ W1) * (Xg @ W2), bf16 MFMA, 128x128xBK64.
// A gathered via tok_list, staged with global_load_lds(16B). Two acc sets.
// ---------------------------------------------------------------------------
__global__ __launch_bounds__(256) void k_gemm12(
    const unsigned short* __restrict__ xbf, const unsigned short* __restrict__ w1t,
    const unsigned short* __restrict__ w2t, unsigned short* __restrict__ H,
    const unsigned int* __restrict__ tok_list, const unsigned int* __restrict__ tile_e,
    const unsigned int* __restrict__ tile_m0, const unsigned int* __restrict__ n_tiles) {
  if (blockIdx.x >= *n_tiles) return;
  int e = (int)tile_e[blockIdx.x];
  int m0 = (int)tile_m0[blockIdx.x];
  int n0 = blockIdx.y * 128;

  __shared__ unsigned short As[128 * BKK];
  __shared__ unsigned short B1s[128 * BKK];
  __shared__ unsigned short B2s[128 * BKK];

  int tid = threadIdx.x, wid = tid >> 6, lane = tid & 63;

  const unsigned short* aP[4];
  const unsigned short* b1P[4];
  const unsigned short* b2P[4];
  int ldsOff[4];
#pragma unroll
  for (int j = 0; j < 4; ++j) {
    int r = (j * 4 + wid) * 8 + (lane >> 3);
    int c8 = (lane & 7) * 8;
    unsigned int tok = tok_list[m0 + r];
    aP[j] = xbf + (size_t)tok * NDIM + c8;
    b1P[j] = w1t + ((size_t)e * NHID + n0 + r) * NDIM + c8;
    b2P[j] = w2t + ((size_t)e * NHID + n0 + r) * NDIM + c8;
    ldsOff[j] = (j * 4 + wid) << 10;  // bytes
  }

  f32x4 acc1[4][4], acc2[4][4];
#pragma unroll
  for (int i = 0; i < 4; ++i)
#pragma unroll
    for (int j = 0; j < 4; ++j) { acc1[i][j] = (f32x4)0.f; acc2[i][j] = (f32x4)0.f; }

  int wr = (wid >> 1) * 64, wc = (wid & 1) * 64;

  for (int k0 = 0; k0 < NDIM; k0 += BKK) {
#pragma unroll
    for (int j = 0; j < 4; ++j) {
      gload16(aP[j] + k0, (char*)As + ldsOff[j]);
      gload16(b1P[j] + k0, (char*)B1s + ldsOff[j]);
      gload16(b2P[j] + k0, (char*)B2s + ldsOff[j]);
    }
    __syncthreads();
#pragma unroll
    for (int ks = 0; ks < 2; ++ks) {
      int ko = ks * 32 + ((lane >> 4) << 3);
      short8 a[4], b1[4], b2[4];
#pragma unroll
      for (int i = 0; i < 4; ++i) {
        a[i] = *(const short8*)(As + (wr + i * 16 + (lane & 15)) * BKK + ko);
        b1[i] = *(const short8*)(B1s + (wc + i * 16 + (lane & 15)) * BKK + ko);
        b2[i] = *(const short8*)(B2s + (wc + i * 16 + (lane & 15)) * BKK + ko);
      }
#pragma unroll
      for (int mi = 0; mi < 4; ++mi)
#pragma unroll
        for (int ni = 0; ni < 4; ++ni) {
          acc1[mi][ni] = __builtin_amdgcn_mfma_f32_16x16x32_bf16(a[mi], b1[ni], acc1[mi][ni], 0, 0, 0);
          acc2[mi][ni] = __builtin_amdgcn_mfma_f32_16x16x32_bf16(a[mi], b2[ni], acc2[mi][ni], 0, 0, 0);
        }
    }
    __syncthreads();
  }

#pragma unroll
  for (int mi = 0; mi < 4; ++mi)
#pragma unroll
    for (int ni = 0; ni < 4; ++ni) {
      f32x4 c1 = acc1[mi][ni], c2 = acc2[mi][ni];
      int col = n0 + wc + ni * 16 + (lane & 15);
#pragma unroll
      for (int q = 0; q < 4; ++q) {
        int slot = m0 + wr + mi * 16 + ((lane >> 4) << 2) + q;
        float hv = silu(c1[q]) * c2[q];
        H[(size_t)slot * NHID + col] = f2bf(hv);
      }
    }
}

// ---------------------------------------------------------------------------
// GEMM3: out[tok] += gate * (H @ W3), atomicAdd epilogue (exactly 2 real
// contributions per output element -> bitwise deterministic).
// ---------------------------------------------------------------------------
__global__ __launch_bounds__(256) void k_gemm3(
    const unsigned short* __restrict__ H, const unsigned short* __restrict__ w3t,
    float* __restrict__ out, const unsigned int* __restrict__ tok_list,
    const float* __restrict__ gate_list, const unsigned int* __restrict__ tile_e,
    const unsigned int* __restrict__ tile_m0, const unsigned int* __restrict__ n_tiles) {
  if (blockIdx.x >= *n_tiles) return;
  int e = (int)tile_e[blockIdx.x];
  int m0 = (int)tile_m0[blockIdx.x];
  int n0 = blockIdx.y * 128;

  __shared__ unsigned short As[128 * BKK];
  __shared__ unsigned short Bs[128 * BKK];

  int tid = threadIdx.x, wid = tid >> 6, lane = tid & 63;

  const unsigned short* aP[4];
  const unsigned short* bP[4];
  int ldsOff[4];
#pragma unroll
  for (int j = 0; j < 4; ++j) {
    int r = (j * 4 + wid) * 8 + (lane >> 3);
    int c8 = (lane & 7) * 8;
    aP[j] = H + (size_t)(m0 + r) * NHID + c8;
    bP[j] = w3t + ((size_t)e * NDIM + n0 + r) * NHID + c8;
    ldsOff[j] = (j * 4 + wid) << 10;
  }

  f32x4 acc[4][4];
#pragma unroll
  for (int i = 0; i < 4; ++i)
#pragma unroll
    for (int j = 0; j < 4; ++j) acc[i][j] = (f32x4)0.f;

  int wr = (wid >> 1) * 64, wc = (wid & 1) * 64;

  for (int k0 = 0; k0 < NHID; k0 += BKK) {
#pragma unroll
    for (int j = 0; j < 4; ++j) {
      gload16(aP[j] + k0, (char*)As + ldsOff[j]);
      gload16(bP[j] + k0, (char*)Bs + ldsOff[j]);
    }
    __syncthreads();
#pragma unroll
    for (int ks = 0; ks < 2; ++ks) {
      int ko = ks * 32 + ((lane >> 4) << 3);
      short8 a[4], b[4];
#pragma unroll
      for (int i = 0; i < 4; ++i) {
        a[i] = *(const short8*)(As + (wr + i * 16 + (lane & 15)) * BKK + ko);
        b[i] = *(const short8*)(Bs + (wc + i * 16 + (lane & 15)) * BKK + ko);
      }
#pragma unroll
      for (int mi = 0; mi < 4; ++mi)
#pragma unroll
        for (int ni = 0; ni < 4; ++ni)
          acc[mi][ni] = __builtin_amdgcn_mfma_f32_16x16x32_bf16(a[mi], b[ni], acc[mi][ni], 0, 0, 0);
    }
    __syncthreads();
  }

#pragma unroll
  for (int mi = 0; mi < 4; ++mi)
#pragma unroll
    for (int q = 0; q < 4; ++q) {
      int slot = m0 + wr + mi * 16 + ((lane >> 4) << 2) + q;
      unsigned int tok = tok_list[slot];
      float g = gate_list[slot];
      float* orow = out + (size_t)tok * NDIM + n0 + wc;
#pragma unroll
      for (int ni = 0; ni < 4; ++ni)
        atomicAdd(orow + ni * 16 + (lane & 15), acc[mi][ni][q] * g);
    }
}

// ---------------------------------------------------------------------------
extern "C" void kernel_launch(void* const* d_in, const int* in_sizes, int n_in,
                              void* d_out, int out_size, void* d_ws, size_t ws_size,
                              hipStream_t stream) {
  const float* x = (const float*)d_in[0];
  const float* rw = (const float*)d_in[1];
  const float* w1 = (const float*)d_in[2];
  const float* w2 = (const float*)d_in[3];
  const float* w3 = (const float*)d_in[4];
  float* out = (float*)d_out;
  char* ws = (char*)d_ws;

  // ws layout: xbf(32MiB) + w3t(32MiB) + H(132MiB) + small lists  ~= 196.5 MiB
  size_t o = 0;
  auto alloc = [&](size_t b) { size_t r = o; o = (o + b + 255) & ~(size_t)255; return r; };
  size_t o_xbf = alloc((size_t)TTOK * NDIM * 2);
  size_t o_w3t = alloc((size_t)NEXP * NDIM * NHID * 2);
  size_t o_H = alloc((size_t)SLOTCAP * NHID * 2);
  size_t o_tok = alloc((size_t)SLOTCAP * 4);
  size_t o_gate = alloc((size_t)SLOTCAP * 4);
  size_t o_te = alloc((size_t)TTOK * 2 * 4);
  size_t o_tg = alloc((size_t)TTOK * 2 * 4);
  size_t o_cnt = alloc(64);
  size_t o_sb = alloc(64);
  size_t o_tle = alloc(MAXTILES * 4 + 64);
  size_t o_tlm = alloc(MAXTILES * 4 + 64);
  size_t o_nt = alloc(64);
  size_t need = o;

  // w1t, w2t live in d_out (64 MiB; only needed before gemm3 zeroes d_out).
  size_t outBytes = (size_t)out_size * sizeof(float);
  size_t wtBytes = (size_t)NEXP * NDIM * NHID * 2;  // 32 MiB each

  if (ws_size < need || outBytes < 2 * wtBytes) {
    // Diagnostic path: absmax will report ws_size in MB.
    hipMemsetAsync(d_out, 0, outBytes, stream);
    k_sentinel<<<1, 64, 0, stream>>>(out, (float)((double)ws_size / 1048576.0));
    return;
  }

  unsigned short* xbf = (unsigned short*)(ws + o_xbf);
  unsigned short* w3t = (unsigned short*)(ws + o_w3t);
  unsigned short* Hbuf = (unsigned short*)(ws + o_H);
  unsigned int* tok_list = (unsigned int*)(ws + o_tok);
  float* gate_list = (float*)(ws + o_gate);
  int* tok_e = (int*)(ws + o_te);
  float* tok_gw = (float*)(ws + o_tg);
  unsigned int* counts = (unsigned int*)(ws + o_cnt);
  unsigned int* slotbase = (unsigned int*)(ws + o_sb);
  unsigned int* tile_e = (unsigned int*)(ws + o_tle);
  unsigned int* tile_m0 = (unsigned int*)(ws + o_tlm);
  unsigned int* n_tiles = (unsigned int*)(ws + o_nt);

  unsigned short* w1t = (unsigned short*)d_out;
  unsigned short* w2t = (unsigned short*)((char*)d_out + wtBytes);

  hipMemsetAsync(counts, 0, 64, stream);

  k_router<<<TTOK / 4, 256, 0, stream>>>(x, rw, xbf, tok_e, tok_gw, counts);
  k_offsets<<<1, 64, 0, stream>>>(counts, slotbase, tile_e, tile_m0, n_tiles);
  k_fill<<<NEXP, 256, 0, stream>>>(tok_e, tok_gw, counts, slotbase, tok_list, gate_list);

  // w1,w2: [e][1024][2048] -> [e][2048][1024] (into d_out scratch);
  // w3: [e][2048][1024] -> [e][1024][2048] (into ws).
  k_tconv<<<dim3(NHID / 64, NDIM / 64, NEXP), 256, 0, stream>>>(w1, w1t, NDIM, NHID);
  k_tconv<<<dim3(NHID / 64, NDIM / 64, NEXP), 256, 0, stream>>>(w2, w2t, NDIM, NHID);
  k_tconv<<<dim3(NDIM / 64, NHID / 64, NEXP), 256, 0, stream>>>(w3, w3t, NHID, NDIM);

  k_gemm12<<<dim3(MAXTILES, NHID / TM), 256, 0, stream>>>(xbf, w1t, w2t, Hbuf, tok_list,
                                                          tile_e, tile_m0, n_tiles);

  // d_out's scratch role is over; zero it for gemm3's atomic accumulation.
  hipMemsetAsync(d_out, 0, outBytes, stream);

  k_gemm3<<<dim3(MAXTILES, NDIM / TM), 256, 0, stream>>>(Hbuf, w3t, out, tok_list, gate_list,
                                                         tile_e, tile_m0, n_tiles);
}

// Round 3
// 1352.732 us; speedup vs baseline: 1.1555x; 1.1555x over previous
//
#include <hip/hip_runtime.h>
#include <stdint.h>

#define TTOK 16384
#define NDIM 1024
#define NHID 2048
#define NEXP 8
#define TM 256
#define MAXT 136
#define SLOTCAP (2 * TTOK + NEXP * TM) /* 34816 */

typedef __attribute__((ext_vector_type(8))) short short8;
typedef __attribute__((ext_vector_type(4))) float f32x4;

__device__ __forceinline__ unsigned short f2bf(float f) {
  unsigned int u = __float_as_uint(f);
  u += 0x7FFFu + ((u >> 16) & 1u);
  return (unsigned short)(u >> 16);
}

__device__ __forceinline__ void gload16(const void* g, void* l) {
  __builtin_amdgcn_global_load_lds(
      (const __attribute__((address_space(1))) unsigned int*)g,
      (__attribute__((address_space(3))) unsigned int*)l, 16, 0, 0);
}

__device__ __forceinline__ float silu(float z) {
  return z / (1.0f + __expf(-z));
}

// ---------------------------------------------------------------------------
// Router: one wave per token. f32 logits, softmax, top-2, renorm gates.
// Also converts the x row to bf16 into ws.
// ---------------------------------------------------------------------------
__global__ void k_router(const float* __restrict__ x, const float* __restrict__ rw,
                         unsigned short* __restrict__ xbf, int* __restrict__ tok_e,
                         float* __restrict__ tok_gw, unsigned int* __restrict__ counts) {
  int t = (blockIdx.x << 2) + (threadIdx.x >> 6);
  int lane = threadIdx.x & 63;
  const float4* xr = (const float4*)(x + (size_t)t * NDIM);

  float4 v[4];
  float d[NEXP];
#pragma unroll
  for (int e = 0; e < NEXP; ++e) d[e] = 0.f;

#pragma unroll
  for (int i = 0; i < 4; ++i) {
    int c = i * 64 + lane;
    v[i] = xr[c];
#pragma unroll
    for (int e = 0; e < NEXP; ++e) {
      float4 w = ((const float4*)(rw + e * NDIM))[c];
      d[e] += v[i].x * w.x + v[i].y * w.y + v[i].z * w.z + v[i].w * w.w;
    }
  }
#pragma unroll
  for (int e = 0; e < NEXP; ++e)
    for (int s = 32; s; s >>= 1) d[e] += __shfl_xor(d[e], s, 64);

  unsigned short* xo = xbf + (size_t)t * NDIM;
#pragma unroll
  for (int i = 0; i < 4; ++i) {
    int c = i * 64 + lane;
    ushort4 u;
    u.x = f2bf(v[i].x); u.y = f2bf(v[i].y); u.z = f2bf(v[i].z); u.w = f2bf(v[i].w);
    ((ushort4*)xo)[c] = u;
  }

  if (lane == 0) {
    float m = d[0];
#pragma unroll
    for (int e = 1; e < NEXP; ++e) m = fmaxf(m, d[e]);
    float ex[NEXP];
#pragma unroll
    for (int e = 0; e < NEXP; ++e) ex[e] = __expf(d[e] - m);
    int e0 = 0;
#pragma unroll
    for (int e = 1; e < NEXP; ++e) if (ex[e] > ex[e0]) e0 = e;
    int e1 = (e0 == 0) ? 1 : 0;
#pragma unroll
    for (int e = 0; e < NEXP; ++e) if (e != e0 && ex[e] > ex[e1]) e1 = e;
    float p0 = ex[e0], p1 = ex[e1];
    float inv = 1.f / (p0 + p1);
    tok_e[2 * t] = e0; tok_e[2 * t + 1] = e1;
    tok_gw[2 * t] = p0 * inv; tok_gw[2 * t + 1] = p1 * inv;
    atomicAdd(&counts[e0], 1u);
    atomicAdd(&counts[e1], 1u);
  }
}

// ---------------------------------------------------------------------------
// Offsets + tile table, 64 threads (redundant compute, parallel writes).
// Tiles padded to TM=256 rows. Unused tile entries get expert=0xFFFFFFFF.
// ---------------------------------------------------------------------------
__global__ void k_offsets(const unsigned int* __restrict__ counts,
                          unsigned int* __restrict__ slotbase, unsigned int* __restrict__ cnt2,
                          unsigned int* __restrict__ tile_e, unsigned int* __restrict__ tile_m0) {
  int l = threadIdx.x;
  unsigned int c[NEXP], base[NEXP], tb[NEXP];
  unsigned int b = 0, t = 0;
#pragma unroll
  for (int e = 0; e < NEXP; ++e) {
    c[e] = counts[e];
    base[e] = b; tb[e] = t;
    unsigned int nt = (c[e] + TM - 1) / TM;
    b += nt * TM; t += nt;
  }
  if (l < NEXP) { slotbase[l] = base[l]; cnt2[l] = 0u; }
  for (int idx = l; idx < MAXT; idx += 64) {
    unsigned int te = 0xFFFFFFFFu, tm = 0;
#pragma unroll
    for (int e = 0; e < NEXP; ++e) {
      unsigned int nt = (c[e] + TM - 1) / TM;
      if ((unsigned)idx >= tb[e] && (unsigned)idx < tb[e] + nt) {
        te = (unsigned)e; tm = base[e] + ((unsigned)idx - tb[e]) * TM;
      }
    }
    tile_e[idx] = te; tile_m0[idx] = tm;
  }
}

// ---------------------------------------------------------------------------
// Fill: one thread per token; atomic slot grab. Slot ORDER is run-varying but
// the final output is bitwise deterministic (2 commutative f32 adds/token;
// slot position never enters the math; pads pre-zeroed).
// ---------------------------------------------------------------------------
__global__ void k_fill(const int* __restrict__ tok_e, const float* __restrict__ tok_gw,
                       const unsigned int* __restrict__ slotbase, unsigned int* __restrict__ cnt2,
                       unsigned int* __restrict__ tok_list, float* __restrict__ gate_list) {
  int t = blockIdx.x * 256 + threadIdx.x;
#pragma unroll
  for (int k = 0; k < 2; ++k) {
    int e = tok_e[2 * t + k];
    float g = tok_gw[2 * t + k];
    unsigned int pos = atomicAdd(&cnt2[e], 1u);
    unsigned int s = slotbase[e] + pos;
    tok_list[s] = (unsigned)t;
    gate_list[s] = g;
  }
}

// ---------------------------------------------------------------------------
// Transpose + f32->bf16 convert: src [b][R][C] f32 -> dst [b][C][R] bf16
// ---------------------------------------------------------------------------
__global__ void k_tconv(const float* __restrict__ src, unsigned short* __restrict__ dst,
                        int R, int C) {
  int b = blockIdx.z;
  src += (size_t)b * R * C;
  dst += (size_t)b * R * C;
  __shared__ unsigned short tile[64][65];
  int bx = blockIdx.x * 64, by = blockIdx.y * 64;
  int tx = threadIdx.x & 15, ty = threadIdx.x >> 4;
#pragma unroll
  for (int rr = 0; rr < 4; ++rr) {
    int rl = rr * 16 + ty;
    float4 v = *(const float4*)(src + (size_t)(by + rl) * C + bx + tx * 4);
    tile[rl][tx * 4 + 0] = f2bf(v.x);
    tile[rl][tx * 4 + 1] = f2bf(v.y);
    tile[rl][tx * 4 + 2] = f2bf(v.z);
    tile[rl][tx * 4 + 3] = f2bf(v.w);
  }
  __syncthreads();
#pragma unroll
  for (int rr = 0; rr < 4; ++rr) {
    int cl = rr * 16 + ty;
    ushort4 u;
    u.x = tile[tx * 4 + 0][cl];
    u.y = tile[tx * 4 + 1][cl];
    u.z = tile[tx * 4 + 2][cl];
    u.w = tile[tx * 4 + 3][cl];
    *(ushort4*)(dst + (size_t)(bx + cl) * R + by + tx * 4) = u;
  }
}

__global__ void k_sentinel(float* __restrict__ out, float v) {
  if (threadIdx.x == 0 && blockIdx.x == 0) out[0] = v;
}

// ---------------------------------------------------------------------------
// GEMM12: 256(M)x128(N) tile, K=1024, BK=64, 8 waves, dbuf LDS (128 KiB),
// T2 XOR-swizzle, fused dual-accumulator (W1,W2). H = silu(XW1)*(XW2) bf16.
// ---------------------------------------------------------------------------
__global__ __launch_bounds__(512, 2) void k_gemm12(
    const unsigned short* __restrict__ xbf, const unsigned short* __restrict__ w1t,
    const unsigned short* __restrict__ w2t, unsigned short* __restrict__ H,
    const unsigned int* __restrict__ tok_list, const unsigned int* __restrict__ tile_e,
    const unsigned int* __restrict__ tile_m0) {
  unsigned int e = tile_e[blockIdx.x];
  if (e > 7u) return;
  int m0 = (int)tile_m0[blockIdx.x];
  int n0 = blockIdx.y * 128;

  __shared__ unsigned short As[2][256 * 64];
  __shared__ unsigned short B1s[2][128 * 64];
  __shared__ unsigned short B2s[2][128 * 64];

  int tid = threadIdx.x, w = tid >> 6, l = tid & 63;
  int rsub = tid >> 3;                                   // 0..63
  int swb = ((tid & 7) * 16) ^ ((rsub & 7) << 4);        // pre-swizzled byte col

  const unsigned short* aS[4];
#pragma unroll
  for (int jj = 0; jj < 4; ++jj) {
    int row = jj * 64 + rsub;
    unsigned int tok = tok_list[m0 + row];
    aS[jj] = xbf + (size_t)tok * NDIM + (swb >> 1);
  }
  const unsigned short* b1S[2];
  const unsigned short* b2S[2];
#pragma unroll
  for (int jj = 0; jj < 2; ++jj) {
    int row = jj * 64 + rsub;
    size_t off = ((size_t)e * NHID + n0 + row) * NDIM + (swb >> 1);
    b1S[jj] = w1t + off;
    b2S[jj] = w2t + off;
  }
  int ldsb = w * 1024;

  f32x4 acc1[8][2], acc2[8][2];
#pragma unroll
  for (int m = 0; m < 8; ++m)
#pragma unroll
    for (int n = 0; n < 2; ++n) { acc1[m][n] = (f32x4)0.f; acc2[m][n] = (f32x4)0.f; }

  int wr = (w >> 2) * 128, wc = (w & 3) * 32;

  auto stage = [&](int kk, int buf) {
    int ke = kk * 64;
#pragma unroll
    for (int jj = 0; jj < 4; ++jj)
      gload16(aS[jj] + ke, (char*)As[buf] + jj * 8192 + ldsb);
#pragma unroll
    for (int jj = 0; jj < 2; ++jj) {
      gload16(b1S[jj] + ke, (char*)B1s[buf] + jj * 8192 + ldsb);
      gload16(b2S[jj] + ke, (char*)B2s[buf] + jj * 8192 + ldsb);
    }
  };

  stage(0, 0);
  __syncthreads();

  for (int t = 0; t < 16; ++t) {
    if (t < 15) stage(t + 1, (t + 1) & 1);
    const char* A = (const char*)As[t & 1];
    const char* B1 = (const char*)B1s[t & 1];
    const char* B2 = (const char*)B2s[t & 1];
#pragma unroll
    for (int ks = 0; ks < 2; ++ks) {
      int kb = ks * 64 + ((l >> 4) << 4);
      short8 a[8], b1[2], b2[2];
#pragma unroll
      for (int m = 0; m < 8; ++m) {
        int r = wr + m * 16 + (l & 15);
        a[m] = *(const short8*)(A + r * 128 + (kb ^ ((r & 7) << 4)));
      }
#pragma unroll
      for (int n = 0; n < 2; ++n) {
        int r = wc + n * 16 + (l & 15);
        int o = r * 128 + (kb ^ ((r & 7) << 4));
        b1[n] = *(const short8*)(B1 + o);
        b2[n] = *(const short8*)(B2 + o);
      }
#pragma unroll
      for (int m = 0; m < 8; ++m)
#pragma unroll
        for (int n = 0; n < 2; ++n) {
          acc1[m][n] = __builtin_amdgcn_mfma_f32_16x16x32_bf16(a[m], b1[n], acc1[m][n], 0, 0, 0);
          acc2[m][n] = __builtin_amdgcn_mfma_f32_16x16x32_bf16(a[m], b2[n], acc2[m][n], 0, 0, 0);
        }
    }
    __syncthreads();
  }

#pragma unroll
  for (int m = 0; m < 8; ++m)
#pragma unroll
    for (int n = 0; n < 2; ++n) {
      int col = n0 + wc + n * 16 + (l & 15);
#pragma unroll
      for (int q = 0; q < 4; ++q) {
        int slot = m0 + wr + m * 16 + ((l >> 4) << 2) + q;
        float hv = silu(acc1[m][n][q]) * acc2[m][n][q];
        H[(size_t)slot * NHID + col] = f2bf(hv);
      }
    }
}

// ---------------------------------------------------------------------------
// GEMM3: 256x256 tile, K=2048, BK=64, dbuf, T2 swizzle; atomicAdd epilogue.
// ---------------------------------------------------------------------------
__global__ __launch_bounds__(512, 2) void k_gemm3(
    const unsigned short* __restrict__ H, const unsigned short* __restrict__ w3t,
    float* __restrict__ out, const unsigned int* __restrict__ tok_list,
    const float* __restrict__ gate_list, const unsigned int* __restrict__ tile_e,
    const unsigned int* __restrict__ tile_m0) {
  unsigned int e = tile_e[blockIdx.x];
  if (e > 7u) return;
  int m0 = (int)tile_m0[blockIdx.x];
  int n0 = blockIdx.y * 256;

  __shared__ unsigned short As[2][256 * 64];
  __shared__ unsigned short Bs[2][256 * 64];

  int tid = threadIdx.x, w = tid >> 6, l = tid & 63;
  int rsub = tid >> 3;
  int swb = ((tid & 7) * 16) ^ ((rsub & 7) << 4);

  const unsigned short* aS[4];
  const unsigned short* bS[4];
#pragma unroll
  for (int jj = 0; jj < 4; ++jj) {
    int row = jj * 64 + rsub;
    aS[jj] = H + (size_t)(m0 + row) * NHID + (swb >> 1);
    bS[jj] = w3t + ((size_t)e * NDIM + n0 + row) * NHID + (swb >> 1);
  }
  int ldsb = w * 1024;

  f32x4 acc[8][4];
#pragma unroll
  for (int m = 0; m < 8; ++m)
#pragma unroll
    for (int n = 0; n < 4; ++n) acc[m][n] = (f32x4)0.f;

  int wr = (w >> 2) * 128, wc = (w & 3) * 64;

  auto stage = [&](int kk, int buf) {
    int ke = kk * 64;
#pragma unroll
    for (int jj = 0; jj < 4; ++jj) {
      gload16(aS[jj] + ke, (char*)As[buf] + jj * 8192 + ldsb);
      gload16(bS[jj] + ke, (char*)Bs[buf] + jj * 8192 + ldsb);
    }
  };

  stage(0, 0);
  __syncthreads();

  for (int t = 0; t < 32; ++t) {
    if (t < 31) stage(t + 1, (t + 1) & 1);
    const char* A = (const char*)As[t & 1];
    const char* B = (const char*)Bs[t & 1];
#pragma unroll
    for (int ks = 0; ks < 2; ++ks) {
      int kb = ks * 64 + ((l >> 4) << 4);
      short8 a[8], b[4];
#pragma unroll
      for (int m = 0; m < 8; ++m) {
        int r = wr + m * 16 + (l & 15);
        a[m] = *(const short8*)(A + r * 128 + (kb ^ ((r & 7) << 4)));
      }
#pragma unroll
      for (int n = 0; n < 4; ++n) {
        int r = wc + n * 16 + (l & 15);
        b[n] = *(const short8*)(B + r * 128 + (kb ^ ((r & 7) << 4)));
      }
#pragma unroll
      for (int m = 0; m < 8; ++m)
#pragma unroll
        for (int n = 0; n < 4; ++n)
          acc[m][n] = __builtin_amdgcn_mfma_f32_16x16x32_bf16(a[m], b[n], acc[m][n], 0, 0, 0);
    }
    __syncthreads();
  }

#pragma unroll
  for (int m = 0; m < 8; ++m)
#pragma unroll
    for (int q = 0; q < 4; ++q) {
      int slot = m0 + wr + m * 16 + ((l >> 4) << 2) + q;
      unsigned int tok = tok_list[slot];
      float g = gate_list[slot];
      float* orow = out + (size_t)tok * NDIM + n0 + wc;
#pragma unroll
      for (int n = 0; n < 4; ++n)
        atomicAdd(orow + n * 16 + (l & 15), acc[m][n][q] * g);
    }
}

// ---------------------------------------------------------------------------
extern "C" void kernel_launch(void* const* d_in, const int* in_sizes, int n_in,
                              void* d_out, int out_size, void* d_ws, size_t ws_size,
                              hipStream_t stream) {
  const float* x = (const float*)d_in[0];
  const float* rw = (const float*)d_in[1];
  const float* w1 = (const float*)d_in[2];
  const float* w2 = (const float*)d_in[3];
  const float* w3 = (const float*)d_in[4];
  float* out = (float*)d_out;
  char* ws = (char*)d_ws;

  size_t o = 0;
  auto alloc = [&](size_t b) { size_t r = o; o = (o + b + 255) & ~(size_t)255; return r; };
  size_t o_xbf = alloc((size_t)TTOK * NDIM * 2);
  size_t o_w3t = alloc((size_t)NEXP * NDIM * NHID * 2);
  size_t o_H = alloc((size_t)SLOTCAP * NHID * 2);
  size_t o_tok = alloc((size_t)SLOTCAP * 4);
  size_t o_gate = alloc((size_t)SLOTCAP * 4);
  size_t o_te = alloc((size_t)TTOK * 2 * 4);
  size_t o_tg = alloc((size_t)TTOK * 2 * 4);
  size_t o_cnt = alloc(64);
  size_t o_cnt2 = alloc(64);
  size_t o_sb = alloc(64);
  size_t o_tle = alloc(MAXT * 4 + 64);
  size_t o_tlm = alloc(MAXT * 4 + 64);
  size_t need = o;

  size_t outBytes = (size_t)out_size * sizeof(float);
  size_t wtBytes = (size_t)NEXP * NDIM * NHID * 2;  // 32 MiB each

  if (ws_size < need || outBytes < 2 * wtBytes) {
    hipMemsetAsync(d_out, 0, outBytes, stream);
    k_sentinel<<<1, 64, 0, stream>>>(out, (float)((double)ws_size / 1048576.0));
    return;
  }

  unsigned short* xbf = (unsigned short*)(ws + o_xbf);
  unsigned short* w3t = (unsigned short*)(ws + o_w3t);
  unsigned short* Hbuf = (unsigned short*)(ws + o_H);
  unsigned int* tok_list = (unsigned int*)(ws + o_tok);
  float* gate_list = (float*)(ws + o_gate);
  int* tok_e = (int*)(ws + o_te);
  float* tok_gw = (float*)(ws + o_tg);
  unsigned int* counts = (unsigned int*)(ws + o_cnt);
  unsigned int* cnt2 = (unsigned int*)(ws + o_cnt2);
  unsigned int* slotbase = (unsigned int*)(ws + o_sb);
  unsigned int* tile_e = (unsigned int*)(ws + o_tle);
  unsigned int* tile_m0 = (unsigned int*)(ws + o_tlm);

  unsigned short* w1t = (unsigned short*)d_out;  // d_out as scratch pre-gemm3
  unsigned short* w2t = (unsigned short*)((char*)d_out + wtBytes);

  hipMemsetAsync(counts, 0, 64, stream);
  hipMemsetAsync(tok_list, 0, (size_t)SLOTCAP * 4, stream);
  hipMemsetAsync(gate_list, 0, (size_t)SLOTCAP * 4, stream);

  k_router<<<TTOK / 4, 256, 0, stream>>>(x, rw, xbf, tok_e, tok_gw, counts);
  k_offsets<<<1, 64, 0, stream>>>(counts, slotbase, cnt2, tile_e, tile_m0);
  k_fill<<<TTOK / 256, 256, 0, stream>>>(tok_e, tok_gw, slotbase, cnt2, tok_list, gate_list);

  k_tconv<<<dim3(NHID / 64, NDIM / 64, NEXP), 256, 0, stream>>>(w1, w1t, NDIM, NHID);
  k_tconv<<<dim3(NHID / 64, NDIM / 64, NEXP), 256, 0, stream>>>(w2, w2t, NDIM, NHID);
  k_tconv<<<dim3(NDIM / 64, NHID / 64, NEXP), 256, 0, stream>>>(w3, w3t, NHID, NDIM);

  k_gemm12<<<dim3(MAXT, NHID / 128), 512, 0, stream>>>(xbf, w1t, w2t, Hbuf, tok_list,
                                                       tile_e, tile_m0);

  hipMemsetAsync(d_out, 0, outBytes, stream);

  k_gemm3<<<dim3(MAXT, NDIM / 256), 512, 0, stream>>>(Hbuf, w3t, out, tok_list, gate_list,
                                                      tile_e, tile_m0);
}

// Round 4
// 1059.443 us; speedup vs baseline: 1.4754x; 1.2768x over previous
//
#include <hip/hip_runtime.h>
#include <stdint.h>

#define TTOK 16384
#define NDIM 1024
#define NHID 2048
#define NEXP 8
#define TM 256
#define MAXT 136
#define SLOTCAP (2 * TTOK + NEXP * TM) /* 34816 */

typedef __attribute__((ext_vector_type(8))) short short8;
typedef __attribute__((ext_vector_type(4))) float f32x4;

__device__ __forceinline__ unsigned short f2bf(float f) {
  unsigned int u = __float_as_uint(f);
  u += 0x7FFFu + ((u >> 16) & 1u);
  return (unsigned short)(u >> 16);
}

__device__ __forceinline__ void gload16(const void* g, void* l) {
  __builtin_amdgcn_global_load_lds(
      (const __attribute__((address_space(1))) unsigned int*)g,
      (__attribute__((address_space(3))) unsigned int*)l, 16, 0, 0);
}

__device__ __forceinline__ float silu(float z) {
  return z / (1.0f + __expf(-z));
}

// ---------------------------------------------------------------------------
// Router: one wave per token. f32 logits, softmax, top-2, renorm gates.
// ---------------------------------------------------------------------------
__global__ void k_router(const float* __restrict__ x, const float* __restrict__ rw,
                         unsigned short* __restrict__ xbf, int* __restrict__ tok_e,
                         float* __restrict__ tok_gw, unsigned int* __restrict__ counts) {
  int t = (blockIdx.x << 2) + (threadIdx.x >> 6);
  int lane = threadIdx.x & 63;
  const float4* xr = (const float4*)(x + (size_t)t * NDIM);

  float4 v[4];
  float d[NEXP];
#pragma unroll
  for (int e = 0; e < NEXP; ++e) d[e] = 0.f;

#pragma unroll
  for (int i = 0; i < 4; ++i) {
    int c = i * 64 + lane;
    v[i] = xr[c];
#pragma unroll
    for (int e = 0; e < NEXP; ++e) {
      float4 w = ((const float4*)(rw + e * NDIM))[c];
      d[e] += v[i].x * w.x + v[i].y * w.y + v[i].z * w.z + v[i].w * w.w;
    }
  }
#pragma unroll
  for (int e = 0; e < NEXP; ++e)
    for (int s = 32; s; s >>= 1) d[e] += __shfl_xor(d[e], s, 64);

  unsigned short* xo = xbf + (size_t)t * NDIM;
#pragma unroll
  for (int i = 0; i < 4; ++i) {
    int c = i * 64 + lane;
    ushort4 u;
    u.x = f2bf(v[i].x); u.y = f2bf(v[i].y); u.z = f2bf(v[i].z); u.w = f2bf(v[i].w);
    ((ushort4*)xo)[c] = u;
  }

  if (lane == 0) {
    float m = d[0];
#pragma unroll
    for (int e = 1; e < NEXP; ++e) m = fmaxf(m, d[e]);
    float ex[NEXP];
#pragma unroll
    for (int e = 0; e < NEXP; ++e) ex[e] = __expf(d[e] - m);
    int e0 = 0;
#pragma unroll
    for (int e = 1; e < NEXP; ++e) if (ex[e] > ex[e0]) e0 = e;
    int e1 = (e0 == 0) ? 1 : 0;
#pragma unroll
    for (int e = 0; e < NEXP; ++e) if (e != e0 && ex[e] > ex[e1]) e1 = e;
    float p0 = ex[e0], p1 = ex[e1];
    float inv = 1.f / (p0 + p1);
    tok_e[2 * t] = e0; tok_e[2 * t + 1] = e1;
    tok_gw[2 * t] = p0 * inv; tok_gw[2 * t + 1] = p1 * inv;
    atomicAdd(&counts[e0], 1u);
    atomicAdd(&counts[e1], 1u);
  }
}

// ---------------------------------------------------------------------------
// Offsets + tile table, 64 threads (redundant compute, parallel writes).
// ---------------------------------------------------------------------------
__global__ void k_offsets(const unsigned int* __restrict__ counts,
                          unsigned int* __restrict__ slotbase, unsigned int* __restrict__ cnt2,
                          unsigned int* __restrict__ tile_e, unsigned int* __restrict__ tile_m0) {
  int l = threadIdx.x;
  unsigned int c[NEXP], base[NEXP], tb[NEXP];
  unsigned int b = 0, t = 0;
#pragma unroll
  for (int e = 0; e < NEXP; ++e) {
    c[e] = counts[e];
    base[e] = b; tb[e] = t;
    unsigned int nt = (c[e] + TM - 1) / TM;
    b += nt * TM; t += nt;
  }
  if (l < NEXP) { slotbase[l] = base[l]; cnt2[l] = 0u; }
  for (int idx = l; idx < MAXT; idx += 64) {
    unsigned int te = 0xFFFFFFFFu, tm = 0;
#pragma unroll
    for (int e = 0; e < NEXP; ++e) {
      unsigned int nt = (c[e] + TM - 1) / TM;
      if ((unsigned)idx >= tb[e] && (unsigned)idx < tb[e] + nt) {
        te = (unsigned)e; tm = base[e] + ((unsigned)idx - tb[e]) * TM;
      }
    }
    tile_e[idx] = te; tile_m0[idx] = tm;
  }
}

// ---------------------------------------------------------------------------
// Fill: hierarchical. LDS histogram for local position, 8 global atomics per
// block for the base (512 total, vs 32768 same-address RMWs before).
// Slot order varies run-to-run; output invariant (2 commutative adds/token).
// ---------------------------------------------------------------------------
__global__ void k_fill(const int* __restrict__ tok_e, const float* __restrict__ tok_gw,
                       const unsigned int* __restrict__ slotbase, unsigned int* __restrict__ cnt2,
                       unsigned int* __restrict__ tok_list, float* __restrict__ gate_list) {
  __shared__ unsigned int hcnt[NEXP];
  __shared__ unsigned int hbase[NEXP];
  int tid = threadIdx.x;
  int t = blockIdx.x * 256 + tid;
  if (tid < NEXP) hcnt[tid] = 0u;
  __syncthreads();
  int e0 = tok_e[2 * t], e1 = tok_e[2 * t + 1];
  float g0 = tok_gw[2 * t], g1 = tok_gw[2 * t + 1];
  unsigned int p0 = atomicAdd(&hcnt[e0], 1u);
  unsigned int p1 = atomicAdd(&hcnt[e1], 1u);
  __syncthreads();
  if (tid < NEXP) hbase[tid] = atomicAdd(&cnt2[tid], hcnt[tid]);
  __syncthreads();
  unsigned int s0 = slotbase[e0] + hbase[e0] + p0;
  unsigned int s1 = slotbase[e1] + hbase[e1] + p1;
  tok_list[s0] = (unsigned)t; gate_list[s0] = g0;
  tok_list[s1] = (unsigned)t; gate_list[s1] = g1;
}

// ---------------------------------------------------------------------------
// Transpose + f32->bf16 convert: src [b][R][C] f32 -> dst [b][C][R] bf16
// ---------------------------------------------------------------------------
__global__ void k_tconv(const float* __restrict__ src, unsigned short* __restrict__ dst,
                        int R, int C) {
  int b = blockIdx.z;
  src += (size_t)b * R * C;
  dst += (size_t)b * R * C;
  __shared__ unsigned short tile[64][65];
  int bx = blockIdx.x * 64, by = blockIdx.y * 64;
  int tx = threadIdx.x & 15, ty = threadIdx.x >> 4;
#pragma unroll
  for (int rr = 0; rr < 4; ++rr) {
    int rl = rr * 16 + ty;
    float4 v = *(const float4*)(src + (size_t)(by + rl) * C + bx + tx * 4);
    tile[rl][tx * 4 + 0] = f2bf(v.x);
    tile[rl][tx * 4 + 1] = f2bf(v.y);
    tile[rl][tx * 4 + 2] = f2bf(v.z);
    tile[rl][tx * 4 + 3] = f2bf(v.w);
  }
  __syncthreads();
#pragma unroll
  for (int rr = 0; rr < 4; ++rr) {
    int cl = rr * 16 + ty;
    ushort4 u;
    u.x = tile[tx * 4 + 0][cl];
    u.y = tile[tx * 4 + 1][cl];
    u.z = tile[tx * 4 + 2][cl];
    u.w = tile[tx * 4 + 3][cl];
    *(ushort4*)(dst + (size_t)(bx + cl) * R + by + tx * 4) = u;
  }
}

__global__ void k_sentinel(float* __restrict__ out, float v) {
  if (threadIdx.x == 0 && blockIdx.x == 0) out[0] = v;
}

// ---------------------------------------------------------------------------
// GEMM12 (unchanged control): 256x128 tile, BK=64, 8 waves, dbuf, T2 swizzle.
// ---------------------------------------------------------------------------
__global__ __launch_bounds__(512, 2) void k_gemm12(
    const unsigned short* __restrict__ xbf, const unsigned short* __restrict__ w1t,
    const unsigned short* __restrict__ w2t, unsigned short* __restrict__ H,
    const unsigned int* __restrict__ tok_list, const unsigned int* __restrict__ tile_e,
    const unsigned int* __restrict__ tile_m0) {
  unsigned int e = tile_e[blockIdx.x];
  if (e > 7u) return;
  int m0 = (int)tile_m0[blockIdx.x];
  int n0 = blockIdx.y * 128;

  __shared__ unsigned short As[2][256 * 64];
  __shared__ unsigned short B1s[2][128 * 64];
  __shared__ unsigned short B2s[2][128 * 64];

  int tid = threadIdx.x, w = tid >> 6, l = tid & 63;
  int rsub = tid >> 3;
  int swb = ((tid & 7) * 16) ^ ((rsub & 7) << 4);

  const unsigned short* aS[4];
#pragma unroll
  for (int jj = 0; jj < 4; ++jj) {
    int row = jj * 64 + rsub;
    unsigned int tok = tok_list[m0 + row];
    aS[jj] = xbf + (size_t)tok * NDIM + (swb >> 1);
  }
  const unsigned short* b1S[2];
  const unsigned short* b2S[2];
#pragma unroll
  for (int jj = 0; jj < 2; ++jj) {
    int row = jj * 64 + rsub;
    size_t off = ((size_t)e * NHID + n0 + row) * NDIM + (swb >> 1);
    b1S[jj] = w1t + off;
    b2S[jj] = w2t + off;
  }
  int ldsb = w * 1024;

  f32x4 acc1[8][2], acc2[8][2];
#pragma unroll
  for (int m = 0; m < 8; ++m)
#pragma unroll
    for (int n = 0; n < 2; ++n) { acc1[m][n] = (f32x4)0.f; acc2[m][n] = (f32x4)0.f; }

  int wr = (w >> 2) * 128, wc = (w & 3) * 32;

  auto stage = [&](int kk, int buf) {
    int ke = kk * 64;
#pragma unroll
    for (int jj = 0; jj < 4; ++jj)
      gload16(aS[jj] + ke, (char*)As[buf] + jj * 8192 + ldsb);
#pragma unroll
    for (int jj = 0; jj < 2; ++jj) {
      gload16(b1S[jj] + ke, (char*)B1s[buf] + jj * 8192 + ldsb);
      gload16(b2S[jj] + ke, (char*)B2s[buf] + jj * 8192 + ldsb);
    }
  };

  stage(0, 0);
  __syncthreads();

  for (int t = 0; t < 16; ++t) {
    if (t < 15) stage(t + 1, (t + 1) & 1);
    const char* A = (const char*)As[t & 1];
    const char* B1 = (const char*)B1s[t & 1];
    const char* B2 = (const char*)B2s[t & 1];
#pragma unroll
    for (int ks = 0; ks < 2; ++ks) {
      int kb = ks * 64 + ((l >> 4) << 4);
      short8 a[8], b1[2], b2[2];
#pragma unroll
      for (int m = 0; m < 8; ++m) {
        int r = wr + m * 16 + (l & 15);
        a[m] = *(const short8*)(A + r * 128 + (kb ^ ((r & 7) << 4)));
      }
#pragma unroll
      for (int n = 0; n < 2; ++n) {
        int r = wc + n * 16 + (l & 15);
        int o = r * 128 + (kb ^ ((r & 7) << 4));
        b1[n] = *(const short8*)(B1 + o);
        b2[n] = *(const short8*)(B2 + o);
      }
#pragma unroll
      for (int m = 0; m < 8; ++m)
#pragma unroll
        for (int n = 0; n < 2; ++n) {
          acc1[m][n] = __builtin_amdgcn_mfma_f32_16x16x32_bf16(a[m], b1[n], acc1[m][n], 0, 0, 0);
          acc2[m][n] = __builtin_amdgcn_mfma_f32_16x16x32_bf16(a[m], b2[n], acc2[m][n], 0, 0, 0);
        }
    }
    __syncthreads();
  }

#pragma unroll
  for (int m = 0; m < 8; ++m)
#pragma unroll
    for (int n = 0; n < 2; ++n) {
      int col = n0 + wc + n * 16 + (l & 15);
#pragma unroll
      for (int q = 0; q < 4; ++q) {
        int slot = m0 + wr + m * 16 + ((l >> 4) << 2) + q;
        float hv = silu(acc1[m][n][q]) * acc2[m][n][q];
        H[(size_t)slot * NHID + col] = f2bf(hv);
      }
    }
}

// ---------------------------------------------------------------------------
// GEMM3: m97-style 128x128 tile, single-buffer 32 KB LDS (5 blocks/CU for
// cross-block overlap), K=2048, BK=64, T2 swizzle; gated atomicAdd epilogue.
// ---------------------------------------------------------------------------
__global__ __launch_bounds__(256, 2) void k_gemm3(
    const unsigned short* __restrict__ H, const unsigned short* __restrict__ w3t,
    float* __restrict__ out, const unsigned int* __restrict__ tok_list,
    const float* __restrict__ gate_list, const unsigned int* __restrict__ tile_e,
    const unsigned int* __restrict__ tile_m0) {
  unsigned int e = tile_e[blockIdx.x >> 1];
  if (e > 7u) return;
  int m0 = (int)tile_m0[blockIdx.x >> 1] + (int)(blockIdx.x & 1) * 128;
  int n0 = blockIdx.y * 128;

  __shared__ unsigned short As[128 * 64];
  __shared__ unsigned short Bs[128 * 64];

  int tid = threadIdx.x, w = tid >> 6, l = tid & 63;
  int rsub = tid >> 3;                               // 0..31
  int swb = ((tid & 7) * 16) ^ ((rsub & 7) << 4);    // pre-swizzled byte col

  const unsigned short* aS[4];
  const unsigned short* bS[4];
#pragma unroll
  for (int jj = 0; jj < 4; ++jj) {
    int row = jj * 32 + rsub;
    aS[jj] = H + (size_t)(m0 + row) * NHID + (swb >> 1);
    bS[jj] = w3t + ((size_t)e * NDIM + n0 + row) * NHID + (swb >> 1);
  }
  int ldsb = w * 1024;

  f32x4 acc[4][4];
#pragma unroll
  for (int m = 0; m < 4; ++m)
#pragma unroll
    for (int n = 0; n < 4; ++n) acc[m][n] = (f32x4)0.f;

  int wr = (w >> 1) * 64, wc = (w & 1) * 64;

  for (int t = 0; t < 32; ++t) {
    int ke = t * 64;
#pragma unroll
    for (int jj = 0; jj < 4; ++jj) {
      gload16(aS[jj] + ke, (char*)As + jj * 4096 + ldsb);
      gload16(bS[jj] + ke, (char*)Bs + jj * 4096 + ldsb);
    }
    __syncthreads();
#pragma unroll
    for (int ks = 0; ks < 2; ++ks) {
      int kb = ks * 64 + ((l >> 4) << 4);
      short8 a[4], b[4];
#pragma unroll
      for (int m = 0; m < 4; ++m) {
        int r = wr + m * 16 + (l & 15);
        a[m] = *(const short8*)((const char*)As + r * 128 + (kb ^ ((r & 7) << 4)));
      }
#pragma unroll
      for (int n = 0; n < 4; ++n) {
        int r = wc + n * 16 + (l & 15);
        b[n] = *(const short8*)((const char*)Bs + r * 128 + (kb ^ ((r & 7) << 4)));
      }
#pragma unroll
      for (int m = 0; m < 4; ++m)
#pragma unroll
        for (int n = 0; n < 4; ++n)
          acc[m][n] = __builtin_amdgcn_mfma_f32_16x16x32_bf16(a[m], b[n], acc[m][n], 0, 0, 0);
    }
    __syncthreads();
  }

#pragma unroll
  for (int m = 0; m < 4; ++m)
#pragma unroll
    for (int q = 0; q < 4; ++q) {
      int slot = m0 + wr + m * 16 + ((l >> 4) << 2) + q;
      unsigned int tok = tok_list[slot];
      float g = gate_list[slot];
      if (g != 0.f) {
        float* orow = out + (size_t)tok * NDIM + n0 + wc;
#pragma unroll
        for (int n = 0; n < 4; ++n)
          atomicAdd(orow + n * 16 + (l & 15), acc[m][n][q] * g);
      }
    }
}

// ---------------------------------------------------------------------------
extern "C" void kernel_launch(void* const* d_in, const int* in_sizes, int n_in,
                              void* d_out, int out_size, void* d_ws, size_t ws_size,
                              hipStream_t stream) {
  const float* x = (const float*)d_in[0];
  const float* rw = (const float*)d_in[1];
  const float* w1 = (const float*)d_in[2];
  const float* w2 = (const float*)d_in[3];
  const float* w3 = (const float*)d_in[4];
  float* out = (float*)d_out;
  char* ws = (char*)d_ws;

  size_t o = 0;
  auto alloc = [&](size_t b) { size_t r = o; o = (o + b + 255) & ~(size_t)255; return r; };
  size_t o_xbf = alloc((size_t)TTOK * NDIM * 2);
  size_t o_w3t = alloc((size_t)NEXP * NDIM * NHID * 2);
  size_t o_H = alloc((size_t)SLOTCAP * NHID * 2);
  size_t o_tok = alloc((size_t)SLOTCAP * 4);
  size_t o_gate = alloc((size_t)SLOTCAP * 4);
  size_t o_te = alloc((size_t)TTOK * 2 * 4);
  size_t o_tg = alloc((size_t)TTOK * 2 * 4);
  size_t o_cnt = alloc(64);
  size_t o_cnt2 = alloc(64);
  size_t o_sb = alloc(64);
  size_t o_tle = alloc(MAXT * 4 + 64);
  size_t o_tlm = alloc(MAXT * 4 + 64);
  size_t need = o;

  size_t outBytes = (size_t)out_size * sizeof(float);
  size_t wtBytes = (size_t)NEXP * NDIM * NHID * 2;  // 32 MiB each

  if (ws_size < need || outBytes < 2 * wtBytes) {
    hipMemsetAsync(d_out, 0, outBytes, stream);
    k_sentinel<<<1, 64, 0, stream>>>(out, (float)((double)ws_size / 1048576.0));
    return;
  }

  unsigned short* xbf = (unsigned short*)(ws + o_xbf);
  unsigned short* w3t = (unsigned short*)(ws + o_w3t);
  unsigned short* Hbuf = (unsigned short*)(ws + o_H);
  unsigned int* tok_list = (unsigned int*)(ws + o_tok);
  float* gate_list = (float*)(ws + o_gate);
  int* tok_e = (int*)(ws + o_te);
  float* tok_gw = (float*)(ws + o_tg);
  unsigned int* counts = (unsigned int*)(ws + o_cnt);
  unsigned int* cnt2 = (unsigned int*)(ws + o_cnt2);
  unsigned int* slotbase = (unsigned int*)(ws + o_sb);
  unsigned int* tile_e = (unsigned int*)(ws + o_tle);
  unsigned int* tile_m0 = (unsigned int*)(ws + o_tlm);

  unsigned short* w1t = (unsigned short*)d_out;  // d_out as scratch pre-gemm3
  unsigned short* w2t = (unsigned short*)((char*)d_out + wtBytes);

  hipMemsetAsync(counts, 0, 64, stream);
  hipMemsetAsync(tok_list, 0, (size_t)SLOTCAP * 4, stream);
  hipMemsetAsync(gate_list, 0, (size_t)SLOTCAP * 4, stream);

  k_router<<<TTOK / 4, 256, 0, stream>>>(x, rw, xbf, tok_e, tok_gw, counts);
  k_offsets<<<1, 64, 0, stream>>>(counts, slotbase, cnt2, tile_e, tile_m0);
  k_fill<<<TTOK / 256, 256, 0, stream>>>(tok_e, tok_gw, slotbase, cnt2, tok_list, gate_list);

  k_tconv<<<dim3(NHID / 64, NDIM / 64, NEXP), 256, 0, stream>>>(w1, w1t, NDIM, NHID);
  k_tconv<<<dim3(NHID / 64, NDIM / 64, NEXP), 256, 0, stream>>>(w2, w2t, NDIM, NHID);
  k_tconv<<<dim3(NDIM / 64, NHID / 64, NEXP), 256, 0, stream>>>(w3, w3t, NHID, NDIM);

  k_gemm12<<<dim3(MAXT, NHID / 128), 512, 0, stream>>>(xbf, w1t, w2t, Hbuf, tok_list,
                                                       tile_e, tile_m0);

  hipMemsetAsync(d_out, 0, outBytes, stream);

  k_gemm3<<<dim3(2 * MAXT, NDIM / 128), 256, 0, stream>>>(Hbuf, w3t, out, tok_list, gate_list,
                                                          tile_e, tile_m0);
}